// Round 1
// baseline (388.370 us; speedup 1.0000x reference)
//
#include <hip/hip_runtime.h>
#include <hip/hip_bf16.h>
#include <math.h>

typedef __bf16 bf16;
typedef __bf16 bf16x2 __attribute__((ext_vector_type(2)));
typedef __bf16 bf16x4 __attribute__((ext_vector_type(4)));
typedef __bf16 bf16x8 __attribute__((ext_vector_type(8)));
typedef float  f32x4  __attribute__((ext_vector_type(4)));

#define NB 4
#define SS 8192
#define DD 1024
#define MM 32768          // NB*SS rows
#define KK 1024
#define NN 1024
#define PI_F 3.14159265358979323846f

// ---- async global->LDS, 16B per lane (guide §5; size must be literal) ----
__device__ __forceinline__ void gl2lds16(const bf16* g, bf16* l) {
    __builtin_amdgcn_global_load_lds(
        (const __attribute__((address_space(1))) void*)g,
        (__attribute__((address_space(3))) void*)l, 16, 0, 0);
}

// ---- cast x (fp32) -> bf16, 4 elems/thread ----
__global__ __launch_bounds__(256) void prep_x(const float* __restrict__ x,
                                              bf16* __restrict__ xb) {
    size_t i = ((size_t)blockIdx.x * 256 + threadIdx.x) * 4;
    float4 v = *(const float4*)&x[i];
    bf16x4 o;
    o[0] = (bf16)v.x; o[1] = (bf16)v.y; o[2] = (bf16)v.z; o[3] = (bf16)v.w;
    *(bf16x4*)&xb[i] = o;
}

// ---- build B^T matrices (bf16): WbT1[n][k] = W_proj[h][k][d]*cos(pi*freqs[n]),
//      WoT[n][k] = W_out[k][n].   n = h*128+d ----
__global__ __launch_bounds__(256) void prep_w(const float* __restrict__ W_proj,
                                              const float* __restrict__ freqs,
                                              const float* __restrict__ W_out,
                                              bf16* __restrict__ WbT1,
                                              bf16* __restrict__ WoT) {
    int idx = blockIdx.x * 256 + threadIdx.x;   // n*1024 + k
    int n = idx >> 10, k = idx & 1023;
    int h = n >> 7, d = n & 127;
    float c = cosf(PI_F * freqs[n]);
    WbT1[idx] = (bf16)(W_proj[(size_t)h * (DD * 128) + (size_t)k * 128 + d] * c);
    WoT[idx]  = (bf16)(W_out[(size_t)k * DD + n]);
}

// ---- 128x128x32 MFMA GEMM, C = A(MxK) * Bt(NxK)^T.  m97 structure. ----
// MODE 0: store bf16 C.  MODE 1: store fp32 (acc + bias[col] + resid[row][col]).
template <int MODE>
__global__ __launch_bounds__(256)
void gemm_bt(const bf16* __restrict__ A, const bf16* __restrict__ Bt,
             bf16* __restrict__ Cb, float* __restrict__ Cf,
             const float* __restrict__ bias, const float* __restrict__ resid) {
    __shared__ bf16 As[128 * 32];
    __shared__ bf16 Bs[128 * 32];
    const int tid  = threadIdx.x;
    const int lane = tid & 63, w = tid >> 6;
    const int wr = w >> 1, wc = w & 1;          // 2x2 waves, each owns 64x64
    const int l15 = lane & 15, l4 = lane >> 4;
    const int row0 = blockIdx.y * 128, col0 = blockIdx.x * 128;
    f32x4 acc[4][4] = {};

    for (int kt = 0; kt < KK; kt += 32) {
#pragma unroll
        for (int it = 0; it < 2; ++it) {
            int p  = it * 4096 + tid * 16;      // byte pos in 8KB tile
            int r  = p >> 6;                    // 64B per row (32 bf16)
            int ko = (p & 63) >> 1;
            gl2lds16(A  + (size_t)(row0 + r) * KK + kt + ko, &As[it * 2048 + w * 512]);
            gl2lds16(Bt + (size_t)(col0 + r) * KK + kt + ko, &Bs[it * 2048 + w * 512]);
        }
        __syncthreads();
        bf16x8 af[4], bg[4];
#pragma unroll
        for (int m = 0; m < 4; ++m)
            af[m] = *(const bf16x8*)&As[(wr * 64 + m * 16 + l15) * 32 + l4 * 8];
#pragma unroll
        for (int n = 0; n < 4; ++n)
            bg[n] = *(const bf16x8*)&Bs[(wc * 64 + n * 16 + l15) * 32 + l4 * 8];
#pragma unroll
        for (int m = 0; m < 4; ++m)
#pragma unroll
            for (int n = 0; n < 4; ++n)
                acc[m][n] = __builtin_amdgcn_mfma_f32_16x16x32_bf16(af[m], bg[n], acc[m][n], 0, 0, 0);
        __syncthreads();
    }

#pragma unroll
    for (int m = 0; m < 4; ++m)
#pragma unroll
        for (int j = 0; j < 4; ++j) {
            int row = row0 + wr * 64 + m * 16 + l4 * 4 + j;
#pragma unroll
            for (int n = 0; n < 4; ++n) {
                int col = col0 + wc * 64 + n * 16 + l15;
                if (MODE == 0) {
                    Cb[(size_t)row * NN + col] = (bf16)acc[m][n][j];
                } else {
                    Cf[(size_t)row * NN + col] =
                        acc[m][n][j] + bias[col] + resid[(size_t)row * NN + col];
                }
            }
        }
}

// ---- per-batch column sums of heads -> hm (fp32 atomics; caller zeroes hm) ----
__global__ __launch_bounds__(256) void colmean_k(const bf16* __restrict__ heads,
                                                 float* __restrict__ hm) {
    int b = blockIdx.y;          // 4
    int sc = blockIdx.x;         // 64 chunks of 128 rows
    int n0 = threadIdx.x * 4;
    float s0 = 0, s1 = 0, s2 = 0, s3 = 0;
    size_t base = ((size_t)b * SS + (size_t)sc * 128) * DD + n0;
    for (int i = 0; i < 128; ++i) {
        bf16x4 v = *(const bf16x4*)&heads[base + (size_t)i * DD];
        s0 += (float)v[0]; s1 += (float)v[1]; s2 += (float)v[2]; s3 += (float)v[3];
    }
    atomicAdd(&hm[b * DD + n0 + 0], s0);
    atomicAdd(&hm[b * DD + n0 + 1], s1);
    atomicAdd(&hm[b * DD + n0 + 2], s2);
    atomicAdd(&hm[b * DD + n0 + 3], s3);
}

// ---- impedance MLP: hm-sums -> pv -> pm -> dp -> gelu/softplus -> imp, coeff ----
__global__ __launch_bounds__(1024) void imp_k(const float* __restrict__ hm,
                                              const float* __restrict__ W_pol,
                                              const float* __restrict__ b_pol,
                                              const float* __restrict__ W_imp1,
                                              const float* __restrict__ b_imp1,
                                              const float* __restrict__ W_imp2,
                                              const float* __restrict__ b_imp2,
                                              float* __restrict__ imp_out,
                                              float* __restrict__ coeff) {
    __shared__ float pm_s[32][32];
    int tid = threadIdx.x;               // 1024 = 4*8*32
    int bh = tid >> 5, p = tid & 31;
    int b = bh >> 3, h = bh & 7;
    float a = b_pol[h * 32 + p];
    for (int d = 0; d < 128; ++d)
        a += hm[b * DD + h * 128 + d] * (1.0f / SS) * W_pol[(h * 128 + d) * 32 + p];
    float pv = tanhf(a);
    pm_s[bh][p] = pv;
    __syncthreads();
    float ss = 0;
    for (int q = 0; q < 32; ++q) ss += pm_s[bh][q] * pm_s[bh][q];
    float pmv = pv / fmaxf(sqrtf(ss), 1e-12f);
    __syncthreads();
    pm_s[bh][p] = pmv;
    __syncthreads();
    if (tid < 256) {
        int b2 = tid >> 6, h2 = (tid >> 3) & 7, g = tid & 7;
        float dp = 0;
        for (int q = 0; q < 32; ++q) dp += pm_s[b2 * 8 + h2][q] * pm_s[b2 * 8 + g][q];
        float a2 = 0;
        for (int k = 0; k < 16; ++k) {
            float zin = dp * W_imp1[k] + b_imp1[k];
            float zg = 0.5f * zin * (1.0f + erff(zin * 0.70710678118654752f));
            a2 += zg * W_imp2[k];
        }
        float spin = a2 + b_imp2[0];
        float impv = (spin > 20.0f) ? spin : log1pf(expf(spin));
        if (h2 == g) impv = 0.0f;
        imp_out[tid] = impv;
        coeff[tid] = (h2 == g) ? 0.0f : 0.1f / (1.0f + impv);
    }
}

// ---- head mixing: merged[n] = heads[n] + (s+1)/S * sum_g coeff[h,g]*heads[g*128+d] ----
__global__ __launch_bounds__(256) void mix_k(const bf16* __restrict__ heads,
                                             const float* __restrict__ coeff,
                                             bf16* __restrict__ merged) {
    __shared__ float cf[64];
    int tid = threadIdx.x;
    size_t r0 = (size_t)blockIdx.x * 4;
    int b = (int)(r0 >> 13);
    if (tid < 64) cf[tid] = coeff[b * 64 + tid];
    __syncthreads();
    int lr = tid >> 6;           // row within block (4 rows/block)
    int d2 = tid & 63;           // element-pair index
    size_t r = r0 + lr;
    int s = (int)(r & (SS - 1));
    float cs = (float)(s + 1) * (1.0f / SS);
    const bf16* hrow = heads + r * DD;
    float v0[8], v1[8];
#pragma unroll
    for (int g = 0; g < 8; ++g) {
        bf16x2 v = *(const bf16x2*)&hrow[g * 128 + d2 * 2];
        v0[g] = (float)v[0]; v1[g] = (float)v[1];
    }
    bf16* mrow = merged + r * DD;
#pragma unroll
    for (int h = 0; h < 8; ++h) {
        float a0 = 0, a1 = 0;
#pragma unroll
        for (int g = 0; g < 8; ++g) {
            float c = cf[h * 8 + g];
            a0 += c * v0[g]; a1 += c * v1[g];
        }
        bf16x2 o;
        o[0] = (bf16)(v0[h] + cs * a0);
        o[1] = (bf16)(v1[h] + cs * a1);
        *(bf16x2*)&mrow[h * 128 + d2 * 2] = o;
    }
}

// ---- in-place row LayerNorm on fp32 z (one row per 256-thread block) ----
__global__ __launch_bounds__(256) void ln_k(float* __restrict__ y,
                                            const float* __restrict__ gamma,
                                            const float* __restrict__ beta) {
    size_t r = blockIdx.x;
    int tid = threadIdx.x;
    float* row = y + r * DD;
    int e0 = tid * 4;
    float4 v = *(const float4*)&row[e0];
    float sum = v.x + v.y + v.z + v.w;
    float sq  = v.x * v.x + v.y * v.y + v.z * v.z + v.w * v.w;
    for (int off = 32; off > 0; off >>= 1) {
        sum += __shfl_down(sum, off);
        sq  += __shfl_down(sq, off);
    }
    __shared__ float red[8];
    int lane = tid & 63, w = tid >> 6;
    if (lane == 0) { red[w] = sum; red[4 + w] = sq; }
    __syncthreads();
    float tot = red[0] + red[1] + red[2] + red[3];
    float tsq = red[4] + red[5] + red[6] + red[7];
    float mu  = tot * (1.0f / DD);
    float var = tsq * (1.0f / DD) - mu * mu;
    float rs  = rsqrtf(var + 1e-5f);
    float4 g4 = *(const float4*)&gamma[e0];
    float4 b4 = *(const float4*)&beta[e0];
    float4 o;
    o.x = (v.x - mu) * rs * g4.x + b4.x;
    o.y = (v.y - mu) * rs * g4.y + b4.y;
    o.z = (v.z - mu) * rs * g4.z + b4.z;
    o.w = (v.w - mu) * rs * g4.w + b4.w;
    *(float4*)&row[e0] = o;
}

extern "C" void kernel_launch(void* const* d_in, const int* in_sizes, int n_in,
                              void* d_out, int out_size, void* d_ws, size_t ws_size,
                              hipStream_t stream) {
    const float* x      = (const float*)d_in[0];
    const float* W_proj = (const float*)d_in[1];
    const float* freqs  = (const float*)d_in[2];
    const float* W_pol  = (const float*)d_in[3];
    const float* b_pol  = (const float*)d_in[4];
    const float* W_imp1 = (const float*)d_in[5];
    const float* b_imp1 = (const float*)d_in[6];
    const float* W_imp2 = (const float*)d_in[7];
    const float* b_imp2 = (const float*)d_in[8];
    const float* W_out  = (const float*)d_in[9];
    const float* b_out  = (const float*)d_in[10];
    const float* gamma  = (const float*)d_in[11];
    const float* beta   = (const float*)d_in[12];

    char* ws = (char*)d_ws;
    bf16* bufA  = (bf16*)ws;                               // 64MB: xb, then merged
    bf16* WbT1  = (bf16*)(ws + ((size_t)64 << 20));        // 2MB
    bf16* WoT   = (bf16*)(ws + ((size_t)66 << 20));        // 2MB
    float* hm   = (float*)(ws + ((size_t)68 << 20));       // 16KB
    float* coeff = (float*)(ws + ((size_t)68 << 20) + 16384); // 1KB
    // peak ws use: ~68MB + 20KB

    float* yout = (float*)d_out;                 // final y (B,S,D) fp32
    bf16* heads = (bf16*)d_out;                  // transient bf16 heads in lower 64MB
    float* imp_out = yout + (size_t)MM * DD;     // output 1: imp (B,8,8)

    hipMemsetAsync(hm, 0, NB * DD * sizeof(float), stream);
    prep_x<<<MM * DD / (256 * 4), 256, 0, stream>>>(x, bufA);
    prep_w<<<(NN * KK) / 256, 256, 0, stream>>>(W_proj, freqs, W_out, WbT1, WoT);

    gemm_bt<0><<<dim3(NN / 128, MM / 128), 256, 0, stream>>>(
        bufA, WbT1, heads, nullptr, nullptr, nullptr);

    colmean_k<<<dim3(64, NB), 256, 0, stream>>>(heads, hm);
    imp_k<<<1, 1024, 0, stream>>>(hm, W_pol, b_pol, W_imp1, b_imp1, W_imp2, b_imp2,
                                  imp_out, coeff);

    mix_k<<<MM / 4, 256, 0, stream>>>(heads, coeff, bufA);  // bufA: xb -> merged

    gemm_bt<1><<<dim3(NN / 128, MM / 128), 256, 0, stream>>>(
        bufA, WoT, nullptr, yout, b_out, x);                // z = proj + b_out + x

    ln_k<<<MM, 256, 0, stream>>>(yout, gamma, beta);
}

// Round 2
// 319.097 us; speedup vs baseline: 1.2171x; 1.2171x over previous
//
#include <hip/hip_runtime.h>
#include <hip/hip_bf16.h>
#include <math.h>

typedef __bf16 bf16;
typedef __bf16 bf16x2 __attribute__((ext_vector_type(2)));
typedef __bf16 bf16x4 __attribute__((ext_vector_type(4)));
typedef __bf16 bf16x8 __attribute__((ext_vector_type(8)));
typedef float  f32x4  __attribute__((ext_vector_type(4)));

#define NB 4
#define SS 8192
#define DD 1024
#define MM 32768          // NB*SS rows
#define KK 1024
#define NN 1024
#define NT 16             // K-tiles of 64
#define PI_F 3.14159265358979323846f

// ---- async global->LDS, 16B per lane ----
__device__ __forceinline__ void gl2lds16(const bf16* g, bf16* l) {
    __builtin_amdgcn_global_load_lds(
        (const __attribute__((address_space(1))) void*)g,
        (__attribute__((address_space(3))) void*)l, 16, 0, 0);
}

// ---- cast x (fp32) -> bf16, 4 elems/thread ----
__global__ __launch_bounds__(256) void prep_x(const float* __restrict__ x,
                                              bf16* __restrict__ xb) {
    size_t i = ((size_t)blockIdx.x * 256 + threadIdx.x) * 4;
    float4 v = *(const float4*)&x[i];
    bf16x4 o;
    o[0] = (bf16)v.x; o[1] = (bf16)v.y; o[2] = (bf16)v.z; o[3] = (bf16)v.w;
    *(bf16x4*)&xb[i] = o;
}

// ---- build B^T matrices (bf16) ----
__global__ __launch_bounds__(256) void prep_w(const float* __restrict__ W_proj,
                                              const float* __restrict__ freqs,
                                              const float* __restrict__ W_out,
                                              bf16* __restrict__ WbT1,
                                              bf16* __restrict__ WoT) {
    int idx = blockIdx.x * 256 + threadIdx.x;   // n*1024 + k
    int n = idx >> 10, k = idx & 1023;
    int h = n >> 7, d = n & 127;
    float c = cosf(PI_F * freqs[n]);
    WbT1[idx] = (bf16)(W_proj[(size_t)h * (DD * 128) + (size_t)k * 128 + d] * c);
    WoT[idx]  = (bf16)(W_out[(size_t)k * DD + n]);
}

// ================== 256x256x64 8-phase MFMA GEMM (T2+T3+T4+T5) ==================
// C = A(MxK) * Bt(NxK)^T.  MODE 0: bf16 C + fused per-batch column sums -> hm.
// MODE 1: fp32 C = acc + bias[col] + resid[row][col].
// LDS 128KB: As0|As1|Bs0|Bs1, each 256rows x 64cols bf16 (row=128B), quad-swizzled:
//   phys_quad = cb ^ (row&7)  (involution; global source pre-swizzled for gl2lds).

#define STAGE(G, grow0, kcol, ldsbase)                                        \
    {                                                                         \
        _Pragma("unroll")                                                     \
        for (int i_ = 0; i_ < 2; ++i_) {                                      \
            int p_ = (i_ * 512 + tid) * 16;                                   \
            int lrow_ = p_ >> 7;                                              \
            int cb_ = ((p_ >> 4) & 7) ^ (lrow_ & 7);                          \
            gl2lds16((G) + (size_t)((grow0) + lrow_) * KK + (kcol) + cb_ * 8, \
                     (ldsbase) + i_ * 4096 + w * 512);                        \
        }                                                                     \
    }

#define LDSF(base, row, cbi) \
    (*(const bf16x8*)&(base)[(row) * 64 + ((((cbi) ^ ((row) & 7))) << 3)])

#define READ_A(MQ)                                                            \
    _Pragma("unroll") for (int m_ = 0; m_ < 4; ++m_)                          \
    _Pragma("unroll") for (int ks_ = 0; ks_ < 2; ++ks_)                       \
        a[m_ * 2 + ks_] = LDSF(Ab, wr * 128 + (MQ) * 64 + m_ * 16 + l15, ks_ * 4 + l4);

#define READ_B(NQ, bfr)                                                       \
    _Pragma("unroll") for (int n_ = 0; n_ < 2; ++n_)                          \
    _Pragma("unroll") for (int ks_ = 0; ks_ < 2; ++ks_)                       \
        bfr[n_ * 2 + ks_] = LDSF(Bb, wc * 64 + (NQ) * 32 + n_ * 16 + l15, ks_ * 4 + l4);

#define MFMA_QUAD(MQ, NQ, bfr)                                                \
    _Pragma("unroll") for (int m_ = 0; m_ < 4; ++m_)                          \
    _Pragma("unroll") for (int n_ = 0; n_ < 2; ++n_)                          \
    _Pragma("unroll") for (int ks_ = 0; ks_ < 2; ++ks_)                       \
        acc[(MQ) * 4 + m_][(NQ) * 2 + n_] =                                   \
            __builtin_amdgcn_mfma_f32_16x16x32_bf16(                          \
                a[m_ * 2 + ks_], bfr[n_ * 2 + ks_],                           \
                acc[(MQ) * 4 + m_][(NQ) * 2 + n_], 0, 0, 0);

#define PHASE_BEGIN                                                           \
    __builtin_amdgcn_sched_barrier(0);                                        \
    __builtin_amdgcn_s_barrier();                                             \
    asm volatile("s_waitcnt lgkmcnt(0)" ::: "memory");                        \
    __builtin_amdgcn_sched_barrier(0);                                        \
    __builtin_amdgcn_s_setprio(1);

#define PHASE_END                                                             \
    __builtin_amdgcn_s_setprio(0);                                            \
    __builtin_amdgcn_sched_barrier(0);                                        \
    __builtin_amdgcn_s_barrier();

template <int MODE>
__global__ __launch_bounds__(512, 2)
void gemm256(const bf16* __restrict__ A, const bf16* __restrict__ Bt,
             bf16* __restrict__ Cb, float* __restrict__ Cf,
             const float* __restrict__ bias, const float* __restrict__ resid,
             float* __restrict__ hm) {
    __shared__ bf16 sm[65536];                 // 128 KB
    const int tid = threadIdx.x;
    const int lane = tid & 63, w = tid >> 6;
    const int wr = w >> 2, wc = w & 3;         // 2(M) x 4(N) waves
    const int l15 = lane & 15, l4 = lane >> 4;

    // XCD-aware bijective swizzle (512 % 8 == 0)
    int wg = blockIdx.x;
    int swz = (wg & 7) * 64 + (wg >> 3);
    const int mt = swz >> 2, ntile = swz & 3;
    const int row0 = mt * 256, col0 = ntile * 256;

    f32x4 acc[8][4] = {};
    bf16x8 a[8], blo[4], bhi[4];

    // prologue: B0(0),B1(0),A0(0),A1(0) then B0(1),B1(1)
    STAGE(Bt, col0 + 0,   0,  sm + 32768);
    STAGE(Bt, col0 + 128, 0,  sm + 32768 + 8192);
    STAGE(A,  row0 + 0,   0,  sm);
    STAGE(A,  row0 + 128, 0,  sm + 8192);
    STAGE(Bt, col0 + 0,   64, sm + 49152);
    STAGE(Bt, col0 + 128, 64, sm + 49152 + 8192);
    asm volatile("s_waitcnt vmcnt(4)" ::: "memory");
    __builtin_amdgcn_s_barrier();

#pragma unroll 2
    for (int u = 0; u < NT; ++u) {
        const int bo = (u & 1) * 16384;
        bf16* Ab = sm + bo;
        bf16* Bb = sm + 32768 + bo;
        bf16* An = sm + (16384 - bo);          // A buffer of tile u+1
        // ---- p1: (mlo,nlo); stage A-half0(u+1) -> other buffer ----
        READ_A(0); READ_B(0, blo);
        if (u + 1 < NT) STAGE(A, row0 + 0, (u + 1) * 64, An);
        PHASE_BEGIN; MFMA_QUAD(0, 0, blo); PHASE_END;
        // ---- p2: (mlo,nhi); stage A-half1(u+1) ----
        READ_B(1, bhi);
        if (u + 1 < NT) STAGE(A, row0 + 128, (u + 1) * 64, An + 8192);
        PHASE_BEGIN; MFMA_QUAD(0, 1, bhi); PHASE_END;
        // ---- p3: (mhi,nhi); stage B-half0(u+2) -> same buffer (B fully read @p2) ----
        READ_A(1);
        if (u + 2 < NT) STAGE(Bt, col0 + 0, (u + 2) * 64, Bb);
        PHASE_BEGIN; MFMA_QUAD(1, 1, bhi); PHASE_END;
        // ---- p4: (mhi,nlo); stage B-half1(u+2); counted vmcnt ----
        if (u + 2 < NT) STAGE(Bt, col0 + 128, (u + 2) * 64, Bb + 8192);
        if (u + 2 < NT) { asm volatile("s_waitcnt vmcnt(4)" ::: "memory"); }
        else            { asm volatile("s_waitcnt vmcnt(0)" ::: "memory"); }
        PHASE_BEGIN; MFMA_QUAD(1, 0, blo); PHASE_END;
    }

    // ---- epilogue ----
    if (MODE == 0) {
        const int batch = row0 >> 13;
#pragma unroll
        for (int mg = 0; mg < 8; ++mg) {
            int rbase = row0 + wr * 128 + (mg >> 2) * 64 + (mg & 3) * 16 + l4 * 4;
#pragma unroll
            for (int j = 0; j < 4; ++j) {
                int row = rbase + j;
#pragma unroll
                for (int ng = 0; ng < 4; ++ng) {
                    int col = col0 + wc * 64 + ng * 16 + l15;
                    Cb[(size_t)row * NN + col] = (bf16)acc[mg][ng][j];
                }
            }
        }
#pragma unroll
        for (int ng = 0; ng < 4; ++ng) {
            float s = 0;
#pragma unroll
            for (int mg = 0; mg < 8; ++mg)
#pragma unroll
                for (int j = 0; j < 4; ++j) s += acc[mg][ng][j];
            int col = col0 + wc * 64 + ng * 16 + l15;
            atomicAdd(&hm[batch * DD + col], s);
        }
    } else {
        float bi[4];
#pragma unroll
        for (int ng = 0; ng < 4; ++ng) bi[ng] = bias[col0 + wc * 64 + ng * 16 + l15];
#pragma unroll
        for (int mg = 0; mg < 8; ++mg) {
            int rbase = row0 + wr * 128 + (mg >> 2) * 64 + (mg & 3) * 16 + l4 * 4;
#pragma unroll
            for (int j = 0; j < 4; ++j) {
                size_t row = rbase + j;
#pragma unroll
                for (int ng = 0; ng < 4; ++ng) {
                    int col = col0 + wc * 64 + ng * 16 + l15;
                    Cf[row * NN + col] = acc[mg][ng][j] + bi[ng] + resid[row * NN + col];
                }
            }
        }
    }
}

// ---- impedance MLP: hm-sums -> pv -> pm -> dp -> gelu/softplus -> imp, coeff ----
__global__ __launch_bounds__(1024) void imp_k(const float* __restrict__ hm,
                                              const float* __restrict__ W_pol,
                                              const float* __restrict__ b_pol,
                                              const float* __restrict__ W_imp1,
                                              const float* __restrict__ b_imp1,
                                              const float* __restrict__ W_imp2,
                                              const float* __restrict__ b_imp2,
                                              float* __restrict__ imp_out,
                                              float* __restrict__ coeff) {
    __shared__ float pm_s[32][32];
    int tid = threadIdx.x;               // 1024 = 4*8*32
    int bh = tid >> 5, p = tid & 31;
    int b = bh >> 3, h = bh & 7;
    float a = b_pol[h * 32 + p];
    for (int d = 0; d < 128; ++d)
        a += hm[b * DD + h * 128 + d] * (1.0f / SS) * W_pol[(h * 128 + d) * 32 + p];
    float pv = tanhf(a);
    pm_s[bh][p] = pv;
    __syncthreads();
    float ss = 0;
    for (int q = 0; q < 32; ++q) ss += pm_s[bh][q] * pm_s[bh][q];
    float pmv = pv / fmaxf(sqrtf(ss), 1e-12f);
    __syncthreads();
    pm_s[bh][p] = pmv;
    __syncthreads();
    if (tid < 256) {
        int b2 = tid >> 6, h2 = (tid >> 3) & 7, g = tid & 7;
        float dp = 0;
        for (int q = 0; q < 32; ++q) dp += pm_s[b2 * 8 + h2][q] * pm_s[b2 * 8 + g][q];
        float a2 = 0;
        for (int k = 0; k < 16; ++k) {
            float zin = dp * W_imp1[k] + b_imp1[k];
            float zg = 0.5f * zin * (1.0f + erff(zin * 0.70710678118654752f));
            a2 += zg * W_imp2[k];
        }
        float spin = a2 + b_imp2[0];
        float impv = (spin > 20.0f) ? spin : log1pf(expf(spin));
        if (h2 == g) impv = 0.0f;
        imp_out[tid] = impv;
        coeff[tid] = (h2 == g) ? 0.0f : 0.1f / (1.0f + impv);
    }
}

// ---- head mixing ----
__global__ __launch_bounds__(256) void mix_k(const bf16* __restrict__ heads,
                                             const float* __restrict__ coeff,
                                             bf16* __restrict__ merged) {
    __shared__ float cf[64];
    int tid = threadIdx.x;
    size_t r0 = (size_t)blockIdx.x * 4;
    int b = (int)(r0 >> 13);
    if (tid < 64) cf[tid] = coeff[b * 64 + tid];
    __syncthreads();
    int lr = tid >> 6;
    int d2 = tid & 63;
    size_t r = r0 + lr;
    int s = (int)(r & (SS - 1));
    float cs = (float)(s + 1) * (1.0f / SS);
    const bf16* hrow = heads + r * DD;
    float v0[8], v1[8];
#pragma unroll
    for (int g = 0; g < 8; ++g) {
        bf16x2 v = *(const bf16x2*)&hrow[g * 128 + d2 * 2];
        v0[g] = (float)v[0]; v1[g] = (float)v[1];
    }
    bf16* mrow = merged + r * DD;
#pragma unroll
    for (int h = 0; h < 8; ++h) {
        float a0 = 0, a1 = 0;
#pragma unroll
        for (int g = 0; g < 8; ++g) {
            float c = cf[h * 8 + g];
            a0 += c * v0[g]; a1 += c * v1[g];
        }
        bf16x2 o;
        o[0] = (bf16)(v0[h] + cs * a0);
        o[1] = (bf16)(v1[h] + cs * a1);
        *(bf16x2*)&mrow[h * 128 + d2 * 2] = o;
    }
}

// ---- in-place row LayerNorm on fp32 ----
__global__ __launch_bounds__(256) void ln_k(float* __restrict__ y,
                                            const float* __restrict__ gamma,
                                            const float* __restrict__ beta) {
    size_t r = blockIdx.x;
    int tid = threadIdx.x;
    float* row = y + r * DD;
    int e0 = tid * 4;
    float4 v = *(const float4*)&row[e0];
    float sum = v.x + v.y + v.z + v.w;
    float sq  = v.x * v.x + v.y * v.y + v.z * v.z + v.w * v.w;
    for (int off = 32; off > 0; off >>= 1) {
        sum += __shfl_down(sum, off);
        sq  += __shfl_down(sq, off);
    }
    __shared__ float red[8];
    int lane = tid & 63, w = tid >> 6;
    if (lane == 0) { red[w] = sum; red[4 + w] = sq; }
    __syncthreads();
    float tot = red[0] + red[1] + red[2] + red[3];
    float tsq = red[4] + red[5] + red[6] + red[7];
    float mu  = tot * (1.0f / DD);
    float var = tsq * (1.0f / DD) - mu * mu;
    float rs  = rsqrtf(var + 1e-5f);
    float4 g4 = *(const float4*)&gamma[e0];
    float4 b4 = *(const float4*)&beta[e0];
    float4 o;
    o.x = (v.x - mu) * rs * g4.x + b4.x;
    o.y = (v.y - mu) * rs * g4.y + b4.y;
    o.z = (v.z - mu) * rs * g4.z + b4.z;
    o.w = (v.w - mu) * rs * g4.w + b4.w;
    *(float4*)&row[e0] = o;
}

extern "C" void kernel_launch(void* const* d_in, const int* in_sizes, int n_in,
                              void* d_out, int out_size, void* d_ws, size_t ws_size,
                              hipStream_t stream) {
    const float* x      = (const float*)d_in[0];
    const float* W_proj = (const float*)d_in[1];
    const float* freqs  = (const float*)d_in[2];
    const float* W_pol  = (const float*)d_in[3];
    const float* b_pol  = (const float*)d_in[4];
    const float* W_imp1 = (const float*)d_in[5];
    const float* b_imp1 = (const float*)d_in[6];
    const float* W_imp2 = (const float*)d_in[7];
    const float* b_imp2 = (const float*)d_in[8];
    const float* W_out  = (const float*)d_in[9];
    const float* b_out  = (const float*)d_in[10];
    const float* gamma  = (const float*)d_in[11];
    const float* beta   = (const float*)d_in[12];

    char* ws = (char*)d_ws;
    bf16* bufA   = (bf16*)ws;                                  // 64MB: xb, then merged
    bf16* WbT1   = (bf16*)(ws + ((size_t)64 << 20));           // 2MB
    bf16* WoT    = (bf16*)(ws + ((size_t)66 << 20));           // 2MB
    float* hm    = (float*)(ws + ((size_t)68 << 20));          // 16KB
    float* coeff = (float*)(ws + ((size_t)68 << 20) + 16384);  // 1KB

    float* yout = (float*)d_out;
    bf16* heads = (bf16*)d_out;                  // transient bf16 heads
    float* imp_out = yout + (size_t)MM * DD;     // output 1: imp (B,8,8)

    hipMemsetAsync(hm, 0, NB * DD * sizeof(float), stream);
    prep_x<<<MM * DD / (256 * 4), 256, 0, stream>>>(x, bufA);
    prep_w<<<(NN * KK) / 256, 256, 0, stream>>>(W_proj, freqs, W_out, WbT1, WoT);

    gemm256<0><<<512, 512, 0, stream>>>(bufA, WbT1, heads, nullptr, nullptr, nullptr, hm);

    imp_k<<<1, 1024, 0, stream>>>(hm, W_pol, b_pol, W_imp1, b_imp1, W_imp2, b_imp2,
                                  imp_out, coeff);

    mix_k<<<MM / 4, 256, 0, stream>>>(heads, coeff, bufA);     // bufA: xb -> merged

    gemm256<1><<<512, 512, 0, stream>>>(bufA, WoT, nullptr, yout, b_out, x, nullptr);

    ln_k<<<MM, 256, 0, stream>>>(yout, gamma, beta);
}

// Round 3
// 280.597 us; speedup vs baseline: 1.3841x; 1.1372x over previous
//
#include <hip/hip_runtime.h>
#include <hip/hip_bf16.h>
#include <math.h>

typedef __bf16 bf16;
typedef __bf16 bf16x2 __attribute__((ext_vector_type(2)));
typedef __bf16 bf16x4 __attribute__((ext_vector_type(4)));
typedef __bf16 bf16x8 __attribute__((ext_vector_type(8)));
typedef float  f32x4  __attribute__((ext_vector_type(4)));

#define NB 4
#define SS 8192
#define DD 1024
#define MM 32768          // NB*SS rows
#define KK 1024
#define NN 1024
#define NT 16             // K-tiles of 64
#define PI_F 3.14159265358979323846f

// d_out row slot layout: each row r owns bytes [4096r, 4096r+4096).
//   stage 1: heads row (bf16, 1024) in first 2KB
//   stage 2: merged row (bf16, 1024) in second 2KB
//   stage 3: z row (bf16, 1024) overwrites first 2KB
//   stage 4: y row (fp32, 1024) overwrites whole 4KB slot

__device__ __forceinline__ void gl2lds16(const bf16* g, bf16* l) {
    __builtin_amdgcn_global_load_lds(
        (const __attribute__((address_space(1))) void*)g,
        (__attribute__((address_space(3))) void*)l, 16, 0, 0);
}

__global__ __launch_bounds__(256) void prep_x(const float* __restrict__ x,
                                              bf16* __restrict__ xb) {
    size_t i = ((size_t)blockIdx.x * 256 + threadIdx.x) * 4;
    float4 v = *(const float4*)&x[i];
    bf16x4 o;
    o[0] = (bf16)v.x; o[1] = (bf16)v.y; o[2] = (bf16)v.z; o[3] = (bf16)v.w;
    *(bf16x4*)&xb[i] = o;
}

__global__ __launch_bounds__(256) void prep_w(const float* __restrict__ W_proj,
                                              const float* __restrict__ freqs,
                                              const float* __restrict__ W_out,
                                              bf16* __restrict__ WbT1,
                                              bf16* __restrict__ WoT) {
    int idx = blockIdx.x * 256 + threadIdx.x;   // n*1024 + k
    int n = idx >> 10, k = idx & 1023;
    int h = n >> 7, d = n & 127;
    float c = cosf(PI_F * freqs[n]);
    WbT1[idx] = (bf16)(W_proj[(size_t)h * (DD * 128) + (size_t)k * 128 + d] * c);
    WoT[idx]  = (bf16)(W_out[(size_t)k * DD + n]);
}

// ============ 256x256x64 pipelined MFMA GEMM: 1 barrier/phase, read-ahead ============
#define STAGE(G, grow0, kcol, ldsbase, LDA)                                    \
    {                                                                          \
        _Pragma("unroll")                                                      \
        for (int i_ = 0; i_ < 2; ++i_) {                                       \
            int p_ = (i_ * 512 + tid) * 16;                                    \
            int lrow_ = p_ >> 7;                                               \
            int cb_ = ((p_ >> 4) & 7) ^ (lrow_ & 7);                           \
            gl2lds16((G) + (size_t)((grow0) + lrow_) * (LDA) + (kcol) + cb_ * 8, \
                     (ldsbase) + i_ * 4096 + w * 512);                         \
        }                                                                      \
    }

#define LDSF(base, row, cbi) \
    (*(const bf16x8*)&(base)[(row) * 64 + ((((cbi) ^ ((row) & 7))) << 3)])

#define READ_A(MQ, base)                                                       \
    _Pragma("unroll") for (int m_ = 0; m_ < 4; ++m_)                           \
    _Pragma("unroll") for (int ks_ = 0; ks_ < 2; ++ks_)                        \
        a[m_ * 2 + ks_] = LDSF(base, wr * 128 + (MQ) * 64 + m_ * 16 + l15, ks_ * 4 + l4);

#define READ_B(NQ, bfr, base)                                                  \
    _Pragma("unroll") for (int n_ = 0; n_ < 2; ++n_)                           \
    _Pragma("unroll") for (int ks_ = 0; ks_ < 2; ++ks_)                        \
        bfr[n_ * 2 + ks_] = LDSF(base, wc * 64 + (NQ) * 32 + n_ * 16 + l15, ks_ * 4 + l4);

#define MFMA_PH(MQ, NQ, bfr)                                                   \
    __builtin_amdgcn_s_setprio(1);                                             \
    _Pragma("unroll") for (int m_ = 0; m_ < 4; ++m_)                           \
    _Pragma("unroll") for (int n_ = 0; n_ < 2; ++n_)                           \
    _Pragma("unroll") for (int ks_ = 0; ks_ < 2; ++ks_)                        \
        acc[(MQ) * 4 + m_][(NQ) * 2 + n_] =                                    \
            __builtin_amdgcn_mfma_f32_16x16x32_bf16(                           \
                a[m_ * 2 + ks_], bfr[n_ * 2 + ks_],                            \
                acc[(MQ) * 4 + m_][(NQ) * 2 + n_], 0, 0, 0);                   \
    __builtin_amdgcn_s_setprio(0);

#define SCHED0 __builtin_amdgcn_sched_barrier(0)
#define BAR    SCHED0; __builtin_amdgcn_s_barrier(); SCHED0
#define LGKM0  asm volatile("s_waitcnt lgkmcnt(0)" ::: "memory"); SCHED0

// MODE 0: C=heads bf16 (stride 2048, first half) + fused column sums -> hm.
// MODE 1: C=z bf16 (stride 2048, first half) = acc + bias[col] + residb[row][col].
template <int MODE>
__global__ __launch_bounds__(512, 2)
void gemm256(const bf16* __restrict__ A, int lda, const bf16* __restrict__ Bt,
             bf16* __restrict__ Cstr, const bf16* __restrict__ residb,
             const float* __restrict__ bias, float* __restrict__ hm) {
    __shared__ bf16 sm[65536];                 // 128 KB
    const int tid = threadIdx.x;
    const int lane = tid & 63, w = tid >> 6;
    const int wr = w >> 2, wc = w & 3;         // 2(M) x 4(N) waves
    const int l15 = lane & 15, l4 = lane >> 4;

    int wg = blockIdx.x;
    int swz = (wg & 7) * 64 + (wg >> 3);       // XCD-aware bijective swizzle
    const int mt = swz >> 2, ntile = swz & 3;
    const int row0 = mt * 256, col0 = ntile * 256;

    f32x4 acc[8][4] = {};
    bf16x8 a[8], blo[4], bhi[4];

    // prologue
    STAGE(Bt, col0 + 0,   0,  sm + 32768,        1024);
    STAGE(Bt, col0 + 128, 0,  sm + 32768 + 8192, 1024);
    STAGE(A,  row0 + 0,   0,  sm,                lda);
    STAGE(A,  row0 + 128, 0,  sm + 8192,         lda);
    STAGE(Bt, col0 + 0,   64, sm + 49152,        1024);
    STAGE(Bt, col0 + 128, 64, sm + 49152 + 8192, 1024);
    asm volatile("s_waitcnt vmcnt(4)" ::: "memory");
    BAR;
    READ_A(0, sm);
    READ_B(0, blo, (sm + 32768));
    SCHED0;

#pragma unroll 2
    for (int u = 0; u < NT; ++u) {
        const int bo = (u & 1) * 16384;
        bf16* Ab = sm + bo;
        bf16* Bb = sm + 32768 + bo;
        bf16* An = sm + (16384 - bo);
        bf16* Bn = sm + 32768 + (16384 - bo);

        // ---- p1: MFMA(0,0,blo); stage A(u+1)h0; prefetch bhi ----
        BAR;
        if (u + 1 < NT) STAGE(A, row0 + 0, (u + 1) * 64, An, lda);
        LGKM0;
        MFMA_PH(0, 0, blo);
        SCHED0;
        READ_B(1, bhi, Bb);
        SCHED0;

        // ---- p2: MFMA(0,1,bhi); stage A(u+1)h1; prefetch a=A[MQ1] ----
        BAR;
        if (u + 1 < NT) STAGE(A, row0 + 128, (u + 1) * 64, An + 8192, lda);
        LGKM0;
        MFMA_PH(0, 1, bhi);
        SCHED0;
        READ_A(1, Ab);
        SCHED0;

        // ---- p3: MFMA(1,1,bhi); stage B(u+2)h0; certify A(u+1) landed ----
        BAR;
        if (u + 2 < NT) STAGE(Bt, col0 + 0, (u + 2) * 64, Bb, 1024);
        LGKM0;
        MFMA_PH(1, 1, bhi);
        SCHED0;
        if (u + 2 < NT) { asm volatile("s_waitcnt vmcnt(2)" ::: "memory"); }
        else            { asm volatile("s_waitcnt vmcnt(0)" ::: "memory"); }
        SCHED0;

        // ---- p4: MFMA(1,0,blo); stage B(u+2)h1; prefetch next tile p1 frags ----
        BAR;
        if (u + 2 < NT) STAGE(Bt, col0 + 128, (u + 2) * 64, Bb + 8192, 1024);
        MFMA_PH(1, 0, blo);
        SCHED0;
        if (u + 1 < NT) {
            READ_A(0, An);
            READ_B(0, blo, Bn);
        }
        SCHED0;
    }

    // ---- epilogue: strided C (row stride 2048 bf16, payload = first 1024) ----
    if (MODE == 0) {
        const int batch = row0 >> 13;
#pragma unroll
        for (int mg = 0; mg < 8; ++mg) {
            int rbase = row0 + wr * 128 + (mg >> 2) * 64 + (mg & 3) * 16 + l4 * 4;
#pragma unroll
            for (int j = 0; j < 4; ++j) {
                size_t row = rbase + j;
#pragma unroll
                for (int ng = 0; ng < 4; ++ng) {
                    int col = col0 + wc * 64 + ng * 16 + l15;
                    Cstr[row * 2048 + col] = (bf16)acc[mg][ng][j];
                }
            }
        }
#pragma unroll
        for (int ng = 0; ng < 4; ++ng) {
            float s = 0;
#pragma unroll
            for (int mg = 0; mg < 8; ++mg)
#pragma unroll
                for (int j = 0; j < 4; ++j) s += acc[mg][ng][j];
            int col = col0 + wc * 64 + ng * 16 + l15;
            atomicAdd(&hm[batch * DD + col], s);
        }
    } else {
        float bi[4];
#pragma unroll
        for (int ng = 0; ng < 4; ++ng) bi[ng] = bias[col0 + wc * 64 + ng * 16 + l15];
#pragma unroll
        for (int mg = 0; mg < 8; ++mg) {
            int rbase = row0 + wr * 128 + (mg >> 2) * 64 + (mg & 3) * 16 + l4 * 4;
#pragma unroll
            for (int j = 0; j < 4; ++j) {
                size_t row = rbase + j;
#pragma unroll
                for (int ng = 0; ng < 4; ++ng) {
                    int col = col0 + wc * 64 + ng * 16 + l15;
                    Cstr[row * 2048 + col] =
                        (bf16)(acc[mg][ng][j] + bi[ng] + (float)residb[row * 1024 + col]);
                }
            }
        }
    }
}

// ---- impedance MLP ----
__global__ __launch_bounds__(1024) void imp_k(const float* __restrict__ hm,
                                              const float* __restrict__ W_pol,
                                              const float* __restrict__ b_pol,
                                              const float* __restrict__ W_imp1,
                                              const float* __restrict__ b_imp1,
                                              const float* __restrict__ W_imp2,
                                              const float* __restrict__ b_imp2,
                                              float* __restrict__ imp_out,
                                              float* __restrict__ coeff) {
    __shared__ float pm_s[32][32];
    int tid = threadIdx.x;
    int bh = tid >> 5, p = tid & 31;
    int b = bh >> 3, h = bh & 7;
    float a = b_pol[h * 32 + p];
    for (int d = 0; d < 128; ++d)
        a += hm[b * DD + h * 128 + d] * (1.0f / SS) * W_pol[(h * 128 + d) * 32 + p];
    float pv = tanhf(a);
    pm_s[bh][p] = pv;
    __syncthreads();
    float ss = 0;
    for (int q = 0; q < 32; ++q) ss += pm_s[bh][q] * pm_s[bh][q];
    float pmv = pv / fmaxf(sqrtf(ss), 1e-12f);
    __syncthreads();
    pm_s[bh][p] = pmv;
    __syncthreads();
    if (tid < 256) {
        int b2 = tid >> 6, h2 = (tid >> 3) & 7, g = tid & 7;
        float dp = 0;
        for (int q = 0; q < 32; ++q) dp += pm_s[b2 * 8 + h2][q] * pm_s[b2 * 8 + g][q];
        float a2 = 0;
        for (int k = 0; k < 16; ++k) {
            float zin = dp * W_imp1[k] + b_imp1[k];
            float zg = 0.5f * zin * (1.0f + erff(zin * 0.70710678118654752f));
            a2 += zg * W_imp2[k];
        }
        float spin = a2 + b_imp2[0];
        float impv = (spin > 20.0f) ? spin : log1pf(expf(spin));
        if (h2 == g) impv = 0.0f;
        imp_out[tid] = impv;
        coeff[tid] = (h2 == g) ? 0.0f : 0.1f / (1.0f + impv);
    }
}

// ---- head mixing: heads (first half of row slot) -> merged (second half) ----
__global__ __launch_bounds__(256) void mix_k(const char* __restrict__ slots,
                                             const float* __restrict__ coeff,
                                             char* __restrict__ slots_w) {
    __shared__ float cf[64];
    int tid = threadIdx.x;
    size_t r0 = (size_t)blockIdx.x * 4;
    int b = (int)(r0 >> 13);
    if (tid < 64) cf[tid] = coeff[b * 64 + tid];
    __syncthreads();
    int lr = tid >> 6;
    int d2 = tid & 63;
    size_t r = r0 + lr;
    int s = (int)(r & (SS - 1));
    float cs = (float)(s + 1) * (1.0f / SS);
    const bf16* hrow = (const bf16*)(slots + r * 4096);
    bf16* mrow = (bf16*)(slots_w + r * 4096 + 2048);
    float v0[8], v1[8];
#pragma unroll
    for (int g = 0; g < 8; ++g) {
        bf16x2 v = *(const bf16x2*)&hrow[g * 128 + d2 * 2];
        v0[g] = (float)v[0]; v1[g] = (float)v[1];
    }
#pragma unroll
    for (int h = 0; h < 8; ++h) {
        float a0 = 0, a1 = 0;
#pragma unroll
        for (int g = 0; g < 8; ++g) {
            float c = cf[h * 8 + g];
            a0 += c * v0[g]; a1 += c * v1[g];
        }
        bf16x2 o;
        o[0] = (bf16)(v0[h] + cs * a0);
        o[1] = (bf16)(v1[h] + cs * a1);
        *(bf16x2*)&mrow[h * 128 + d2 * 2] = o;
    }
}

// ---- LayerNorm: read bf16 z from first 2KB of row slot, write fp32 y over slot ----
__global__ __launch_bounds__(256) void ln_k(char* __restrict__ slots,
                                            const float* __restrict__ gamma,
                                            const float* __restrict__ beta) {
    size_t r = blockIdx.x;
    int tid = threadIdx.x;
    const bf16* zrow = (const bf16*)(slots + r * 4096);
    float* yrow = (float*)(slots + r * 4096);
    int e0 = tid * 4;
    bf16x4 zv = *(const bf16x4*)&zrow[e0];
    float vx = (float)zv[0], vy = (float)zv[1], vz = (float)zv[2], vw = (float)zv[3];
    float sum = vx + vy + vz + vw;
    float sq  = vx * vx + vy * vy + vz * vz + vw * vw;
    for (int off = 32; off > 0; off >>= 1) {
        sum += __shfl_down(sum, off);
        sq  += __shfl_down(sq, off);
    }
    __shared__ float red[8];
    int lane = tid & 63, wv = tid >> 6;
    if (lane == 0) { red[wv] = sum; red[4 + wv] = sq; }
    __syncthreads();
    float tot = red[0] + red[1] + red[2] + red[3];
    float tsq = red[4] + red[5] + red[6] + red[7];
    float mu  = tot * (1.0f / DD);
    float var = tsq * (1.0f / DD) - mu * mu;
    float rs  = rsqrtf(var + 1e-5f);
    float4 g4 = *(const float4*)&gamma[e0];
    float4 b4 = *(const float4*)&beta[e0];
    float4 o;
    o.x = (vx - mu) * rs * g4.x + b4.x;
    o.y = (vy - mu) * rs * g4.y + b4.y;
    o.z = (vz - mu) * rs * g4.z + b4.z;
    o.w = (vw - mu) * rs * g4.w + b4.w;
    *(float4*)&yrow[e0] = o;
}

extern "C" void kernel_launch(void* const* d_in, const int* in_sizes, int n_in,
                              void* d_out, int out_size, void* d_ws, size_t ws_size,
                              hipStream_t stream) {
    const float* x      = (const float*)d_in[0];
    const float* W_proj = (const float*)d_in[1];
    const float* freqs  = (const float*)d_in[2];
    const float* W_pol  = (const float*)d_in[3];
    const float* b_pol  = (const float*)d_in[4];
    const float* W_imp1 = (const float*)d_in[5];
    const float* b_imp1 = (const float*)d_in[6];
    const float* W_imp2 = (const float*)d_in[7];
    const float* b_imp2 = (const float*)d_in[8];
    const float* W_out  = (const float*)d_in[9];
    const float* b_out  = (const float*)d_in[10];
    const float* gamma  = (const float*)d_in[11];
    const float* beta   = (const float*)d_in[12];

    char* ws = (char*)d_ws;
    bf16* xb     = (bf16*)ws;                                  // 64MB
    bf16* WbT1   = (bf16*)(ws + ((size_t)64 << 20));           // 2MB
    bf16* WoT    = (bf16*)(ws + ((size_t)66 << 20));           // 2MB
    float* hm    = (float*)(ws + ((size_t)68 << 20));          // 16KB
    float* coeff = (float*)(ws + ((size_t)68 << 20) + 16384);  // 1KB

    char* slots = (char*)d_out;                      // 128MB of 4KB row slots
    float* imp_out = (float*)d_out + (size_t)MM * DD;

    hipMemsetAsync(hm, 0, NB * DD * sizeof(float), stream);
    prep_x<<<MM * DD / (256 * 4), 256, 0, stream>>>(x, xb);
    prep_w<<<(NN * KK) / 256, 256, 0, stream>>>(W_proj, freqs, W_out, WbT1, WoT);

    // GEMM1: heads -> first half of row slots (+ hm column sums)
    gemm256<0><<<512, 512, 0, stream>>>(xb, 1024, WbT1, (bf16*)slots,
                                        nullptr, nullptr, hm);

    imp_k<<<1, 1024, 0, stream>>>(hm, W_pol, b_pol, W_imp1, b_imp1, W_imp2, b_imp2,
                                  imp_out, coeff);

    mix_k<<<MM / 4, 256, 0, stream>>>(slots, coeff, slots);    // heads -> merged

    // GEMM2: A = merged (second half, stride 2048); z -> first half of slots
    gemm256<1><<<512, 512, 0, stream>>>((const bf16*)slots + 1024, 2048, WoT,
                                        (bf16*)slots, xb, b_out, nullptr);

    ln_k<<<MM, 256, 0, stream>>>(slots, gamma, beta);
}

// Round 4
// 269.879 us; speedup vs baseline: 1.4391x; 1.0397x over previous
//
#include <hip/hip_runtime.h>
#include <hip/hip_bf16.h>
#include <math.h>

typedef __bf16 bf16;
typedef __bf16 bf16x2 __attribute__((ext_vector_type(2)));
typedef __bf16 bf16x4 __attribute__((ext_vector_type(4)));
typedef __bf16 bf16x8 __attribute__((ext_vector_type(8)));
typedef float  f32x4  __attribute__((ext_vector_type(4)));

#define NB 4
#define SS 8192
#define DD 1024
#define MM 32768
#define KK 1024
#define NN 1024
#define NT 16             // K-tiles of 64
#define PI_F 3.14159265358979323846f

__device__ __forceinline__ void gl2lds16(const bf16* g, bf16* l) {
    __builtin_amdgcn_global_load_lds(
        (const __attribute__((address_space(1))) void*)g,
        (__attribute__((address_space(3))) void*)l, 16, 0, 0);
}

// ---- fused prep: x->bf16 cast (blocks [0,MM)), W build + hm zero (blocks [MM,MM+4096)) ----
__global__ __launch_bounds__(256) void prep_all(const float* __restrict__ x,
                                                bf16* __restrict__ xb,
                                                const float* __restrict__ W_proj,
                                                const float* __restrict__ freqs,
                                                const float* __restrict__ W_out,
                                                bf16* __restrict__ WbT1,
                                                bf16* __restrict__ WoT,
                                                float* __restrict__ hm) {
    int blk = blockIdx.x;
    if (blk < MM) {
        size_t i = (size_t)blk * 1024 + threadIdx.x * 4;
        float4 v = *(const float4*)&x[i];
        bf16x4 o;
        o[0] = (bf16)v.x; o[1] = (bf16)v.y; o[2] = (bf16)v.z; o[3] = (bf16)v.w;
        *(bf16x4*)&xb[i] = o;
    } else {
        int idx = (blk - MM) * 256 + threadIdx.x;   // n*1024 + k
        int n = idx >> 10, k = idx & 1023;
        int h = n >> 7, d = n & 127;
        float c = cosf(PI_F * freqs[n]);
        WbT1[idx] = (bf16)(W_proj[(size_t)h * (DD * 128) + (size_t)k * 128 + d] * c);
        WoT[idx]  = (bf16)(W_out[(size_t)k * DD + n]);
        if (idx < NB * DD) hm[idx] = 0.0f;
    }
}

// ============ 256x256x64 pipelined MFMA GEMM: 1 barrier/phase, reg addressing ============
#define SCHED0 __builtin_amdgcn_sched_barrier(0)
#define BAR    SCHED0; __builtin_amdgcn_s_barrier(); SCHED0
#define LGKM0  asm volatile("s_waitcnt lgkmcnt(0)" ::: "memory"); SCHED0

#define STG(g0, g1, uk, ldsBase)                                  \
    gl2lds16((g0) + (uk), &sm[(ldsBase) + w * 512]);              \
    gl2lds16((g1) + (uk), &sm[(ldsBase) + 4096 + w * 512]);

#define READ_A2(MQ, ab)                                                          \
    _Pragma("unroll") for (int m_ = 0; m_ < 4; ++m_) {                           \
        a[m_ * 2 + 0] = *(const bf16x8*)&sm[(ab) + aoff0 + ((MQ)*64 + m_*16)*64];\
        a[m_ * 2 + 1] = *(const bf16x8*)&sm[(ab) + aoff1 + ((MQ)*64 + m_*16)*64];\
    }
#define READ_B2(NQ, bfr, bb)                                                     \
    _Pragma("unroll") for (int n_ = 0; n_ < 2; ++n_) {                           \
        bfr[n_ * 2 + 0] = *(const bf16x8*)&sm[(bb) + boff0 + ((NQ)*32 + n_*16)*64];\
        bfr[n_ * 2 + 1] = *(const bf16x8*)&sm[(bb) + boff1 + ((NQ)*32 + n_*16)*64];\
    }

#define MFMA_Q(MQ, NQ, bfr)                                                    \
    _Pragma("unroll") for (int m_ = 0; m_ < 4; ++m_)                           \
    _Pragma("unroll") for (int n_ = 0; n_ < 2; ++n_)                           \
    _Pragma("unroll") for (int ks_ = 0; ks_ < 2; ++ks_)                        \
        acc[(MQ) * 4 + m_][(NQ) * 2 + n_] =                                    \
            __builtin_amdgcn_mfma_f32_16x16x32_bf16(                           \
                a[m_ * 2 + ks_], bfr[n_ * 2 + ks_],                            \
                acc[(MQ) * 4 + m_][(NQ) * 2 + n_], 0, 0, 0);

// MODE 0: C=heads bf16 (stride 2048) + fused column sums -> hm.
// MODE 1: C=z bf16 (stride 2048) = acc + bias[col] + residb[row][col].
template <int MODE>
__global__ __launch_bounds__(512, 2)
void gemm256(const bf16* __restrict__ A, int lda, const bf16* __restrict__ Bt,
             bf16* __restrict__ Cstr, const bf16* __restrict__ residb,
             const float* __restrict__ bias, float* __restrict__ hm) {
    __shared__ bf16 sm[65536];                 // 128 KB
    const int tid = threadIdx.x;
    const int lane = tid & 63, w = tid >> 6;
    const int wr = w >> 2, wc = w & 3;         // 2(M) x 4(N) waves
    const int l15 = lane & 15, l4 = lane >> 4;

    int wg = blockIdx.x;
    int swz = (wg & 7) * 64 + (wg >> 3);       // XCD-aware bijective swizzle
    const int mt = swz >> 2, ntile = swz & 3;
    const int row0 = mt * 256, col0 = ntile * 256;

    // LDS frag-read offsets (elements); swizzle collapses to per-lane constants
    const int aoff0 = (wr * 128 + l15) * 64 + ((l4 ^ (l15 & 7)) << 3);
    const int aoff1 = aoff0 ^ 32;
    const int boff0 = (wc * 64 + l15) * 64 + ((l4 ^ (l15 & 7)) << 3);
    const int boff1 = boff0 ^ 32;

    // global stage pointers (per-thread, pre-swizzled source)
    const int srow = tid >> 3;                       // 0..63
    const int scb  = (tid & 7) ^ (srow & 7);
    const bf16* gA00 = A + (size_t)(row0 + srow) * lda + scb * 8;
    const bf16* gA01 = gA00 + (size_t)64 * lda;
    const bf16* gA10 = gA00 + (size_t)128 * lda;
    const bf16* gA11 = gA00 + (size_t)192 * lda;
    const bf16* gB00 = Bt + (size_t)(col0 + srow) * 1024 + scb * 8;
    const bf16* gB01 = gB00 + 64 * 1024;
    const bf16* gB10 = gB00 + 128 * 1024;
    const bf16* gB11 = gB00 + 192 * 1024;

    f32x4 acc[8][4] = {};
    bf16x8 a[8], blo[4], bhi[4];

    // prologue: B(0), A(0), B(1)
    STG(gB00, gB01, 0,  32768);
    STG(gB10, gB11, 0,  32768 + 8192);
    STG(gA00, gA01, 0,  0);
    STG(gA10, gA11, 0,  8192);
    STG(gB00, gB01, 64, 49152);
    STG(gB10, gB11, 64, 49152 + 8192);
    asm volatile("s_waitcnt vmcnt(4)" ::: "memory");
    BAR;
    READ_A2(0, 0);
    READ_B2(0, blo, 32768);
    SCHED0;

#pragma unroll 2
    for (int u = 0; u < NT; ++u) {
        const int bo = (u & 1) * 16384;
        const int ab = bo, bb = 32768 + bo;
        const int an = 16384 - bo, bn = 32768 + (16384 - bo);
        const int uk1 = (u + 1) * 64, uk2 = (u + 2) * 64;

        // ---- p1: MFMA(0,0,blo); stage A(u+1)h0; prefetch bhi ----
        BAR;
        if (u + 1 < NT) { STG(gA00, gA01, uk1, an); }
        LGKM0;
        __builtin_amdgcn_s_setprio(1);
        MFMA_Q(0, 0, blo);
        READ_B2(1, bhi, bb);
        __builtin_amdgcn_s_setprio(0);
        SCHED0;

        // ---- p2: MFMA(0,1,bhi); stage A(u+1)h1; prefetch a=A[MQ1] ----
        BAR;
        if (u + 1 < NT) { STG(gA10, gA11, uk1, an + 8192); }
        LGKM0;
        __builtin_amdgcn_s_setprio(1);
        MFMA_Q(0, 1, bhi);
        READ_A2(1, ab);
        __builtin_amdgcn_s_setprio(0);
        SCHED0;

        // ---- p3: MFMA(1,1,bhi); stage B(u+2)h0; certify A(u+1) landed ----
        BAR;
        if (u + 2 < NT) { STG(gB00, gB01, uk2, bb); }
        LGKM0;
        __builtin_amdgcn_s_setprio(1);
        MFMA_Q(1, 1, bhi);
        __builtin_amdgcn_s_setprio(0);
        if (u + 2 < NT) { asm volatile("s_waitcnt vmcnt(2)" ::: "memory"); }
        else            { asm volatile("s_waitcnt vmcnt(0)" ::: "memory"); }
        SCHED0;

        // ---- p4: MFMA(1,0,blo); stage B(u+2)h1; prefetch next-tile p1 frags ----
        BAR;
        if (u + 2 < NT) { STG(gB10, gB11, uk2, bb + 8192); }
        __builtin_amdgcn_s_setprio(1);
        MFMA_Q(1, 0, blo);
        if (u + 1 < NT) {
            READ_A2(0, an);
            READ_B2(0, blo, bn);
        }
        __builtin_amdgcn_s_setprio(0);
        SCHED0;
    }

    // ---- epilogue: strided C (row stride 2048 bf16, payload = first 1024) ----
    if (MODE == 0) {
        const int batch = row0 >> 13;
#pragma unroll
        for (int mg = 0; mg < 8; ++mg) {
            int rbase = row0 + wr * 128 + (mg >> 2) * 64 + (mg & 3) * 16 + l4 * 4;
#pragma unroll
            for (int j = 0; j < 4; ++j) {
                size_t row = rbase + j;
#pragma unroll
                for (int ng = 0; ng < 4; ++ng) {
                    int col = col0 + wc * 64 + ng * 16 + l15;
                    Cstr[row * 2048 + col] = (bf16)acc[mg][ng][j];
                }
            }
        }
#pragma unroll
        for (int ng = 0; ng < 4; ++ng) {
            float s = 0;
#pragma unroll
            for (int mg = 0; mg < 8; ++mg)
#pragma unroll
                for (int j = 0; j < 4; ++j) s += acc[mg][ng][j];
            int col = col0 + wc * 64 + ng * 16 + l15;
            atomicAdd(&hm[batch * DD + col], s);
        }
    } else {
        float bi[4];
#pragma unroll
        for (int ng = 0; ng < 4; ++ng) bi[ng] = bias[col0 + wc * 64 + ng * 16 + l15];
#pragma unroll
        for (int mg = 0; mg < 8; ++mg) {
            int rbase = row0 + wr * 128 + (mg >> 2) * 64 + (mg & 3) * 16 + l4 * 4;
#pragma unroll
            for (int j = 0; j < 4; ++j) {
                size_t row = rbase + j;
#pragma unroll
                for (int ng = 0; ng < 4; ++ng) {
                    int col = col0 + wc * 64 + ng * 16 + l15;
                    Cstr[row * 2048 + col] =
                        (bf16)(acc[mg][ng][j] + bi[ng] + (float)residb[row * 1024 + col]);
                }
            }
        }
    }
}

// ---- impedance MLP ----
__global__ __launch_bounds__(1024) void imp_k(const float* __restrict__ hm,
                                              const float* __restrict__ W_pol,
                                              const float* __restrict__ b_pol,
                                              const float* __restrict__ W_imp1,
                                              const float* __restrict__ b_imp1,
                                              const float* __restrict__ W_imp2,
                                              const float* __restrict__ b_imp2,
                                              float* __restrict__ imp_out,
                                              float* __restrict__ coeff) {
    __shared__ float pm_s[32][32];
    int tid = threadIdx.x;
    int bh = tid >> 5, p = tid & 31;
    int b = bh >> 3, h = bh & 7;
    float a = b_pol[h * 32 + p];
    for (int d = 0; d < 128; ++d)
        a += hm[b * DD + h * 128 + d] * (1.0f / SS) * W_pol[(h * 128 + d) * 32 + p];
    float pv = tanhf(a);
    pm_s[bh][p] = pv;
    __syncthreads();
    float ss = 0;
    for (int q = 0; q < 32; ++q) ss += pm_s[bh][q] * pm_s[bh][q];
    float pmv = pv / fmaxf(sqrtf(ss), 1e-12f);
    __syncthreads();
    pm_s[bh][p] = pmv;
    __syncthreads();
    if (tid < 256) {
        int b2 = tid >> 6, h2 = (tid >> 3) & 7, g = tid & 7;
        float dp = 0;
        for (int q = 0; q < 32; ++q) dp += pm_s[b2 * 8 + h2][q] * pm_s[b2 * 8 + g][q];
        float a2 = 0;
        for (int k = 0; k < 16; ++k) {
            float zin = dp * W_imp1[k] + b_imp1[k];
            float zg = 0.5f * zin * (1.0f + erff(zin * 0.70710678118654752f));
            a2 += zg * W_imp2[k];
        }
        float spin = a2 + b_imp2[0];
        float impv = (spin > 20.0f) ? spin : log1pf(expf(spin));
        if (h2 == g) impv = 0.0f;
        imp_out[tid] = impv;
        coeff[tid] = (h2 == g) ? 0.0f : 0.1f / (1.0f + impv);
    }
}

// ---- head mixing: heads (first half of row slot) -> merged (second half) ----
__global__ __launch_bounds__(256) void mix_k(const char* __restrict__ slots,
                                             const float* __restrict__ coeff,
                                             char* __restrict__ slots_w) {
    __shared__ float cf[64];
    int tid = threadIdx.x;
    size_t r0 = (size_t)blockIdx.x * 4;
    int b = (int)(r0 >> 13);
    if (tid < 64) cf[tid] = coeff[b * 64 + tid];
    __syncthreads();
    int lr = tid >> 6;
    int d2 = tid & 63;
    size_t r = r0 + lr;
    int s = (int)(r & (SS - 1));
    float cs = (float)(s + 1) * (1.0f / SS);
    const bf16* hrow = (const bf16*)(slots + r * 4096);
    bf16* mrow = (bf16*)(slots_w + r * 4096 + 2048);
    float v0[8], v1[8];
#pragma unroll
    for (int g = 0; g < 8; ++g) {
        bf16x2 v = *(const bf16x2*)&hrow[g * 128 + d2 * 2];
        v0[g] = (float)v[0]; v1[g] = (float)v[1];
    }
#pragma unroll
    for (int h = 0; h < 8; ++h) {
        float a0 = 0, a1 = 0;
#pragma unroll
        for (int g = 0; g < 8; ++g) {
            float c = cf[h * 8 + g];
            a0 += c * v0[g]; a1 += c * v1[g];
        }
        bf16x2 o;
        o[0] = (bf16)(v0[h] + cs * a0);
        o[1] = (bf16)(v1[h] + cs * a1);
        *(bf16x2*)&mrow[h * 128 + d2 * 2] = o;
    }
}

// ---- LayerNorm: read bf16 z from first 2KB of row slot, write fp32 y over slot ----
__global__ __launch_bounds__(256) void ln_k(char* __restrict__ slots,
                                            const float* __restrict__ gamma,
                                            const float* __restrict__ beta) {
    size_t r = blockIdx.x;
    int tid = threadIdx.x;
    const bf16* zrow = (const bf16*)(slots + r * 4096);
    float* yrow = (float*)(slots + r * 4096);
    int e0 = tid * 4;
    bf16x4 zv = *(const bf16x4*)&zrow[e0];
    float vx = (float)zv[0], vy = (float)zv[1], vz = (float)zv[2], vw = (float)zv[3];
    float sum = vx + vy + vz + vw;
    float sq  = vx * vx + vy * vy + vz * vz + vw * vw;
    for (int off = 32; off > 0; off >>= 1) {
        sum += __shfl_down(sum, off);
        sq  += __shfl_down(sq, off);
    }
    __shared__ float red[8];
    int lane = tid & 63, wv = tid >> 6;
    if (lane == 0) { red[wv] = sum; red[4 + wv] = sq; }
    __syncthreads();
    float tot = red[0] + red[1] + red[2] + red[3];
    float tsq = red[4] + red[5] + red[6] + red[7];
    float mu  = tot * (1.0f / DD);
    float var = tsq * (1.0f / DD) - mu * mu;
    float rs  = rsqrtf(var + 1e-5f);
    float4 g4 = *(const float4*)&gamma[e0];
    float4 b4 = *(const float4*)&beta[e0];
    float4 o;
    o.x = (vx - mu) * rs * g4.x + b4.x;
    o.y = (vy - mu) * rs * g4.y + b4.y;
    o.z = (vz - mu) * rs * g4.z + b4.z;
    o.w = (vw - mu) * rs * g4.w + b4.w;
    *(float4*)&yrow[e0] = o;
}

extern "C" void kernel_launch(void* const* d_in, const int* in_sizes, int n_in,
                              void* d_out, int out_size, void* d_ws, size_t ws_size,
                              hipStream_t stream) {
    const float* x      = (const float*)d_in[0];
    const float* W_proj = (const float*)d_in[1];
    const float* freqs  = (const float*)d_in[2];
    const float* W_pol  = (const float*)d_in[3];
    const float* b_pol  = (const float*)d_in[4];
    const float* W_imp1 = (const float*)d_in[5];
    const float* b_imp1 = (const float*)d_in[6];
    const float* W_imp2 = (const float*)d_in[7];
    const float* b_imp2 = (const float*)d_in[8];
    const float* W_out  = (const float*)d_in[9];
    const float* b_out  = (const float*)d_in[10];
    const float* gamma  = (const float*)d_in[11];
    const float* beta   = (const float*)d_in[12];

    char* ws = (char*)d_ws;
    bf16* xb     = (bf16*)ws;                                  // 64MB
    bf16* WbT1   = (bf16*)(ws + ((size_t)64 << 20));           // 2MB
    bf16* WoT    = (bf16*)(ws + ((size_t)66 << 20));           // 2MB
    float* hm    = (float*)(ws + ((size_t)68 << 20));          // 16KB
    float* coeff = (float*)(ws + ((size_t)68 << 20) + 16384);  // 1KB

    char* slots = (char*)d_out;                      // 128MB of 4KB row slots
    float* imp_out = (float*)d_out + (size_t)MM * DD;

    prep_all<<<MM + 4096, 256, 0, stream>>>(x, xb, W_proj, freqs, W_out,
                                            WbT1, WoT, hm);

    // GEMM1: heads -> first half of row slots (+ hm column sums)
    gemm256<0><<<512, 512, 0, stream>>>(xb, 1024, WbT1, (bf16*)slots,
                                        nullptr, nullptr, hm);

    imp_k<<<1, 1024, 0, stream>>>(hm, W_pol, b_pol, W_imp1, b_imp1, W_imp2, b_imp2,
                                  imp_out, coeff);

    mix_k<<<MM / 4, 256, 0, stream>>>(slots, coeff, slots);    // heads -> merged

    // GEMM2: A = merged (second half, stride 2048); z -> first half of slots
    gemm256<1><<<512, 512, 0, stream>>>((const bf16*)slots + 1024, 2048, WoT,
                                        (bf16*)slots, xb, b_out, nullptr);

    ln_k<<<MM, 256, 0, stream>>>(slots, gamma, beta);
}